// Round 1
// baseline (1538.445 us; speedup 1.0000x reference)
//
#include <hip/hip_runtime.h>
#include <hip/hip_bf16.h>
#include <hip/hip_fp16.h>

#define T_ 2048
#define B_ 64
#define NIN_ 128
#define H_ 256
#define NOUT_ 128
#define TB_ (T_*B_)
#define BH_ (B_*H_)
#define TBLK_ (T_/8)   // 256 blocks of 8 timesteps

typedef _Float16 h8 __attribute__((ext_vector_type(8)));
typedef _Float16 h4 __attribute__((ext_vector_type(4)));
typedef _Float16 h2 __attribute__((ext_vector_type(2)));
typedef float f32x4 __attribute__((ext_vector_type(4)));

// LDS-only barrier: do NOT drain vmcnt (global loads/stores stay in flight).
#define BAR_LGKM() asm volatile("s_waitcnt lgkmcnt(0)\n\ts_barrier" ::: "memory")

__device__ __forceinline__ h8 cvt8(float4 a, float4 b) {
    h8 r;
    r[0] = (_Float16)a.x; r[1] = (_Float16)a.y; r[2] = (_Float16)a.z; r[3] = (_Float16)a.w;
    r[4] = (_Float16)b.x; r[5] = (_Float16)b.y; r[6] = (_Float16)b.z; r[7] = (_Float16)b.w;
    return r;
}
__device__ __forceinline__ h8 ld_cvt8(const float* __restrict__ p) {
    const float4* q = (const float4*)p;
    return cvt8(q[0], q[1]);
}

// ---------------------------------------------------------------------------
// K1: xp2[b][t/8][j][t%8] (f16) = x[t][b][:] @ W_ih^T + (b_ih+b_hh)
// (unchanged from baseline)
// ---------------------------------------------------------------------------
__global__ __launch_bounds__(256, 2) void k1_xproj(
    const float* __restrict__ x,
    const float* __restrict__ w_ih,
    const float* __restrict__ b_ih,
    const float* __restrict__ b_hh,
    _Float16* __restrict__ xp2)
{
    const int tid = threadIdx.x;
    const int lane = tid & 63, wave = tid >> 6;
    const int m = lane & 15, quad = lane >> 4;
    const int b  = blockIdx.x >> 4;
    const int tc = blockIdx.x & 15;

    h8 af[4][4];
    #pragma unroll
    for (int i = 0; i < 4; ++i)
        #pragma unroll
        for (int kt = 0; kt < 4; ++kt)
            af[i][kt] = ld_cvt8(w_ih + (size_t)(wave*64 + i*16 + m) * NIN_ + kt*32 + quad*8);

    float bias[4][4];
    #pragma unroll
    for (int i = 0; i < 4; ++i)
        #pragma unroll
        for (int r = 0; r < 4; ++r) {
            int c = wave*64 + i*16 + quad*4 + r;
            bias[i][r] = b_ih[c] + b_hh[c];
        }

    __shared__ __align__(16) _Float16 st2[2][256 * 24];   // [j][t] stride 24

    float4 xr[4][2];
    {
        const int t0 = tc * 128;
        #pragma unroll
        for (int kt = 0; kt < 4; ++kt) {
            const float4* q = (const float4*)(x + ((size_t)(t0 + m) * B_ + b) * NIN_ + kt*32 + quad*8);
            xr[kt][0] = q[0]; xr[kt][1] = q[1];
        }
    }

    for (int rt = 0; rt < 8; ++rt) {
        const int t0 = tc * 128 + rt * 16;

        h8 bf[4];
        #pragma unroll
        for (int kt = 0; kt < 4; ++kt) bf[kt] = cvt8(xr[kt][0], xr[kt][1]);

        if (rt < 7) {
            #pragma unroll
            for (int kt = 0; kt < 4; ++kt) {
                const float4* q = (const float4*)(x + ((size_t)(t0 + 16 + m) * B_ + b) * NIN_ + kt*32 + quad*8);
                xr[kt][0] = q[0]; xr[kt][1] = q[1];
            }
        }

        f32x4 acc[4];
        #pragma unroll
        for (int i = 0; i < 4; ++i) acc[i] = (f32x4){0,0,0,0};
        #pragma unroll
        for (int i = 0; i < 4; ++i)
            #pragma unroll
            for (int kt = 0; kt < 4; ++kt)
                acc[i] = __builtin_amdgcn_mfma_f32_16x16x32_f16(af[i][kt], bf[kt], acc[i], 0, 0, 0);

        const int p = rt & 1;
        #pragma unroll
        for (int i = 0; i < 4; ++i)
            #pragma unroll
            for (int r = 0; r < 4; ++r) {
                int j = wave*64 + i*16 + quad*4 + r;
                st2[p][j*24 + m] = (_Float16)(acc[i][r] + bias[i][r]);
            }
        BAR_LGKM();
        {
            const int j = tid;
            const h8* row = (const h8*)&st2[p][j*24];
            h8 v0 = row[0], v1 = row[1];
            const int blk = t0 >> 3;
            _Float16* dst = xp2 + ((size_t)(b * TBLK_ + blk) * H_ + j) * 8;
            *(h8*)dst            = v0;
            *(h8*)(dst + H_*8)   = v1;
        }
    }
}

// ---------------------------------------------------------------------------
// K2: sequential scan via full-rate v_dot2_f32_f16 (VALU), not MFMA.
// Rationale: the MFMA path costs 32 MFMA x ~19.4 cyc = 620 cyc/step per SIMD
// (A-rows are a broadcast -> 15/16 of matrix work redundant). The matvec on
// VALU dot2 costs 128 instr x 2 cyc = 256 cyc/step per SIMD.
//   - lane j owns output column j; W_hh row j held in 128 VGPRs (one-time load)
//   - h broadcast from LDS as 32x ds_read_b128 (uniform addr -> conflict-free)
//   - each 16B h-chunk's VGPR pairs (01/23/45/67) feed fdot2 directly (no repack)
//   - 4 interleaved f32 accumulator chains (dep distance 4 >= VALU latency)
// Everything else (xp2 prefetch 1 block ahead, double-buffered h in LDS,
// 1 lgkm-only barrier/step, hs stores) identical to the proven kernel.
// ---------------------------------------------------------------------------
__global__ __launch_bounds__(256, 1) void k2_scan(
    const _Float16* __restrict__ xp2,      // [B][T/8][H][8] f16
    const float* __restrict__ w_hh,        // [H][H] f32
    _Float16* __restrict__ hs)             // [T][B][H] f16
{
    const int tid = threadIdx.x;
    const int b = blockIdx.x;
    const int j = tid;                      // owned output column

    // W_hh row j as 32 h8 chunks (128 VGPRs)
    h8 w[32];
    #pragma unroll
    for (int c = 0; c < 32; ++c)
        w[c] = ld_cvt8(w_hh + (size_t)j * H_ + c*8);

    __shared__ __align__(16) _Float16 hb[2][256];
    hb[0][tid] = (_Float16)0.0f;
    __syncthreads();

    const _Float16* xq = xp2 + ((size_t)b * TBLK_ * H_ + j) * 8;
    _Float16*       hsl = hs + (size_t)b * H_ + j;

    h8 pf = *(const h8*)xq;                 // block 0

#define K2_STEP(T, RB, WB, XV)                                                 \
    {                                                                          \
        const h8* hp = (const h8*)&RB[0];                                      \
        float a0 = 0.f, a1 = 0.f, a2 = 0.f, a3 = 0.f;                          \
        _Pragma("unroll")                                                      \
        for (int c = 0; c < 32; ++c) {                                         \
            h8 hc = hp[c];                                                     \
            a0 = __builtin_amdgcn_fdot2(__builtin_shufflevector(hc, hc, 0, 1), \
                                        __builtin_shufflevector(w[c], w[c], 0, 1), a0, false); \
            a1 = __builtin_amdgcn_fdot2(__builtin_shufflevector(hc, hc, 2, 3), \
                                        __builtin_shufflevector(w[c], w[c], 2, 3), a1, false); \
            a2 = __builtin_amdgcn_fdot2(__builtin_shufflevector(hc, hc, 4, 5), \
                                        __builtin_shufflevector(w[c], w[c], 4, 5), a2, false); \
            a3 = __builtin_amdgcn_fdot2(__builtin_shufflevector(hc, hc, 6, 7), \
                                        __builtin_shufflevector(w[c], w[c], 6, 7), a3, false); \
        }                                                                      \
        float sv = ((a0 + a1) + (a2 + a3)) + (XV);                             \
        float e  = __expf(2.0f * sv);                                          \
        float hn = fmaf(-2.0f, __builtin_amdgcn_rcpf(e + 1.0f), 1.0f);         \
        _Float16 h16 = (_Float16)hn;                                           \
        WB[j] = h16;                                                           \
        hsl[(size_t)(T) * BH_] = h16;                                          \
        BAR_LGKM();                                                            \
    }

    for (int tb = 0; tb < TBLK_; ++tb) {
        h8 cur = pf;                         // waits on load issued 1 block ago
        const int tnb = (tb + 1 < TBLK_) ? tb + 1 : TBLK_ - 1;
        pf = *(const h8*)(xq + (size_t)tnb * (H_ * 8));   // in flight for 8 steps
        const int t = tb * 8;
        K2_STEP(t + 0, hb[0], hb[1], (float)cur[0])
        K2_STEP(t + 1, hb[1], hb[0], (float)cur[1])
        K2_STEP(t + 2, hb[0], hb[1], (float)cur[2])
        K2_STEP(t + 3, hb[1], hb[0], (float)cur[3])
        K2_STEP(t + 4, hb[0], hb[1], (float)cur[4])
        K2_STEP(t + 5, hb[1], hb[0], (float)cur[5])
        K2_STEP(t + 6, hb[0], hb[1], (float)cur[6])
        K2_STEP(t + 7, hb[1], hb[0], (float)cur[7])
    }
#undef K2_STEP
}

// ---------------------------------------------------------------------------
// K3: out[TB][128](f32) = hs[TB][256](f16) @ W_out^T + b_out   (MFMA C^T)
// (unchanged from baseline)
// ---------------------------------------------------------------------------
__global__ __launch_bounds__(256, 2) void k3_out(
    const _Float16* __restrict__ hs,
    const float* __restrict__ w_out,
    const float* __restrict__ b_out,
    float* __restrict__ out)
{
    const int tid = threadIdx.x;
    const int lane = tid & 63, wave = tid >> 6;
    const int m = lane & 15, quad = lane >> 4;

    h8 af[2][8];
    #pragma unroll
    for (int i = 0; i < 2; ++i)
        #pragma unroll
        for (int kt = 0; kt < 8; ++kt)
            af[i][kt] = ld_cvt8(w_out + (size_t)(wave*32 + i*16 + m) * H_ + kt*32 + quad*8);

    float bias[2][4];
    #pragma unroll
    for (int i = 0; i < 2; ++i)
        #pragma unroll
        for (int r = 0; r < 4; ++r)
            bias[i][r] = b_out[wave*32 + i*16 + quad*4 + r];

    __shared__ __align__(16) float st[2][16][132];

    h8 bf[8];
    {
        const size_t n0 = (size_t)blockIdx.x * 128;
        #pragma unroll
        for (int kt = 0; kt < 8; ++kt)
            bf[kt] = *(const h8*)(hs + (n0 + m) * H_ + kt*32 + quad*8);
    }

    for (int rt = 0; rt < 8; ++rt) {
        const size_t n0 = (size_t)blockIdx.x * 128 + rt * 16;

        h8 cur[8];
        #pragma unroll
        for (int kt = 0; kt < 8; ++kt) cur[kt] = bf[kt];

        if (rt < 7) {
            #pragma unroll
            for (int kt = 0; kt < 8; ++kt)
                bf[kt] = *(const h8*)(hs + (n0 + 16 + m) * H_ + kt*32 + quad*8);
        }

        f32x4 acc[2];
        #pragma unroll
        for (int i = 0; i < 2; ++i) acc[i] = (f32x4){0,0,0,0};
        #pragma unroll
        for (int i = 0; i < 2; ++i)
            #pragma unroll
            for (int kt = 0; kt < 8; ++kt)
                acc[i] = __builtin_amdgcn_mfma_f32_16x16x32_f16(af[i][kt], cur[kt], acc[i], 0, 0, 0);

        const int p = rt & 1;
        #pragma unroll
        for (int i = 0; i < 2; ++i) {
            f32x4 v;
            #pragma unroll
            for (int r = 0; r < 4; ++r) v[r] = acc[i][r] + bias[i][r];
            *(f32x4*)&st[p][m][wave*32 + i*16 + quad*4] = v;
        }
        BAR_LGKM();
        #pragma unroll
        for (int it = 0; it < 2; ++it) {
            int idx = tid + it*256;
            int r = idx >> 5, c4 = (idx & 31) * 4;
            f32x4 v = *(const f32x4*)&st[p][r][c4];
            *(f32x4*)(out + (n0 + r) * NOUT_ + c4) = v;
        }
    }
}

extern "C" void kernel_launch(void* const* d_in, const int* in_sizes, int n_in,
                              void* d_out, int out_size, void* d_ws, size_t ws_size,
                              hipStream_t stream) {
    const float* x     = (const float*)d_in[0];
    const float* w_ih  = (const float*)d_in[1];
    const float* w_hh  = (const float*)d_in[2];
    const float* b_ih  = (const float*)d_in[3];
    const float* b_hh  = (const float*)d_in[4];
    const float* w_out = (const float*)d_in[5];
    const float* b_out = (const float*)d_in[6];

    _Float16* xp2   = (_Float16*)d_ws;                 // 67.1 MB [B][T/8][H][8]
    _Float16* hsbuf = xp2 + (size_t)TB_ * H_;          // 67.1 MB [T][B][H]

    k1_xproj<<<1024, 256, 0, stream>>>(x, w_ih, b_ih, b_hh, xp2);
    k2_scan <<<B_,   256, 0, stream>>>(xp2, w_hh, hsbuf);
    k3_out  <<<1024, 256, 0, stream>>>(hsbuf, w_out, b_out, (float*)d_out);
}

// Round 2
// 1018.240 us; speedup vs baseline: 1.5109x; 1.5109x over previous
//
#include <hip/hip_runtime.h>
#include <hip/hip_bf16.h>
#include <hip/hip_fp16.h>

#define T_ 2048
#define B_ 64
#define NIN_ 128
#define H_ 256
#define NOUT_ 128
#define TB_ (T_*B_)
#define BH_ (B_*H_)
#define TBLK_ (T_/8)   // 256 blocks of 8 timesteps

typedef _Float16 h8 __attribute__((ext_vector_type(8)));
typedef _Float16 h4 __attribute__((ext_vector_type(4)));
typedef float f32x4 __attribute__((ext_vector_type(4)));

// LDS-only barrier: do NOT drain vmcnt (global loads/stores stay in flight).
#define BAR_LGKM() asm volatile("s_waitcnt lgkmcnt(0)\n\ts_barrier" ::: "memory")

__device__ __forceinline__ h8 cvt8(float4 a, float4 b) {
    h8 r;
    r[0] = (_Float16)a.x; r[1] = (_Float16)a.y; r[2] = (_Float16)a.z; r[3] = (_Float16)a.w;
    r[4] = (_Float16)b.x; r[5] = (_Float16)b.y; r[6] = (_Float16)b.z; r[7] = (_Float16)b.w;
    return r;
}
__device__ __forceinline__ h8 ld_cvt8(const float* __restrict__ p) {
    const float4* q = (const float4*)p;
    return cvt8(q[0], q[1]);
}

// ---------------------------------------------------------------------------
// K1: xp2[b][t/8][j][t%8] (f16) = x[t][b][:] @ W_ih^T + (b_ih+b_hh)
// (unchanged from proven baseline)
// ---------------------------------------------------------------------------
__global__ __launch_bounds__(256, 2) void k1_xproj(
    const float* __restrict__ x,
    const float* __restrict__ w_ih,
    const float* __restrict__ b_ih,
    const float* __restrict__ b_hh,
    _Float16* __restrict__ xp2)
{
    const int tid = threadIdx.x;
    const int lane = tid & 63, wave = tid >> 6;
    const int m = lane & 15, quad = lane >> 4;
    const int b  = blockIdx.x >> 4;
    const int tc = blockIdx.x & 15;

    h8 af[4][4];
    #pragma unroll
    for (int i = 0; i < 4; ++i)
        #pragma unroll
        for (int kt = 0; kt < 4; ++kt)
            af[i][kt] = ld_cvt8(w_ih + (size_t)(wave*64 + i*16 + m) * NIN_ + kt*32 + quad*8);

    float bias[4][4];
    #pragma unroll
    for (int i = 0; i < 4; ++i)
        #pragma unroll
        for (int r = 0; r < 4; ++r) {
            int c = wave*64 + i*16 + quad*4 + r;
            bias[i][r] = b_ih[c] + b_hh[c];
        }

    __shared__ __align__(16) _Float16 st2[2][256 * 24];   // [j][t] stride 24

    float4 xr[4][2];
    {
        const int t0 = tc * 128;
        #pragma unroll
        for (int kt = 0; kt < 4; ++kt) {
            const float4* q = (const float4*)(x + ((size_t)(t0 + m) * B_ + b) * NIN_ + kt*32 + quad*8);
            xr[kt][0] = q[0]; xr[kt][1] = q[1];
        }
    }

    for (int rt = 0; rt < 8; ++rt) {
        const int t0 = tc * 128 + rt * 16;

        h8 bf[4];
        #pragma unroll
        for (int kt = 0; kt < 4; ++kt) bf[kt] = cvt8(xr[kt][0], xr[kt][1]);

        if (rt < 7) {
            #pragma unroll
            for (int kt = 0; kt < 4; ++kt) {
                const float4* q = (const float4*)(x + ((size_t)(t0 + 16 + m) * B_ + b) * NIN_ + kt*32 + quad*8);
                xr[kt][0] = q[0]; xr[kt][1] = q[1];
            }
        }

        f32x4 acc[4];
        #pragma unroll
        for (int i = 0; i < 4; ++i) acc[i] = (f32x4){0,0,0,0};
        #pragma unroll
        for (int i = 0; i < 4; ++i)
            #pragma unroll
            for (int kt = 0; kt < 4; ++kt)
                acc[i] = __builtin_amdgcn_mfma_f32_16x16x32_f16(af[i][kt], bf[kt], acc[i], 0, 0, 0);

        const int p = rt & 1;
        #pragma unroll
        for (int i = 0; i < 4; ++i)
            #pragma unroll
            for (int r = 0; r < 4; ++r) {
                int j = wave*64 + i*16 + quad*4 + r;
                st2[p][j*24 + m] = (_Float16)(acc[i][r] + bias[i][r]);
            }
        BAR_LGKM();
        {
            const int j = tid;
            const h8* row = (const h8*)&st2[p][j*24];
            h8 v0 = row[0], v1 = row[1];
            const int blk = t0 >> 3;
            _Float16* dst = xp2 + ((size_t)(b * TBLK_ + blk) * H_ + j) * 8;
            *(h8*)dst            = v0;
            *(h8*)(dst + H_*8)   = v1;
        }
    }
}

// ---------------------------------------------------------------------------
// K2: sequential scan via MFMA, 64 WGs (one batch each), now 512 threads
// (8 waves, 2 per SIMD). N=256 split 32 cols/wave: 16 MFMA/wave/step;
// per-SIMD matrix-pipe work unchanged (2x16 = 32 MFMA = ~620 cyc) but the
// two waves per SIMD interleave their serial phases (tanh/ds_write/barrier/
// ds_read latency, ~380 cyc exposed at 1 wave/SIMD) with each other's MFMA
// issue -> step time ~pipe-bound.
// Rows of A are h broadcast to all 16 M-rows -> all acc regs equal; quad
// pairs (0,2) and (1,3) own the same column, only quads 0-1 write.
// xp2 consumed one uint4 (8 timesteps) per lane, loaded one block ahead.
// h double-buffered in LDS; 1 lgkm-only barrier/step.
// ---------------------------------------------------------------------------
__global__ __launch_bounds__(512, 1) void k2_scan(
    const _Float16* __restrict__ xp2,      // [B][T/8][H][8] f16
    const float* __restrict__ w_hh,        // [H][H] f32
    _Float16* __restrict__ hs)             // [T][B][H] f16
{
    const int tid = threadIdx.x;
    const int lane = tid & 63, wave = tid >> 6;   // wave 0..7
    const int n = lane & 15, quad = lane >> 4;
    const int b = blockIdx.x;
    const int tsel = quad & 1;                    // which of the wave's 2 N-tiles
    const int j = wave*32 + tsel*16 + n;          // owned output column
    const bool writer = (quad < 2);               // quads 2,3 duplicate 0,1

    // B-frags (W_hh) for this wave's 32 columns: 2 tiles x 8 K-steps, 64 VGPRs
    h8 bf[2][8];
    #pragma unroll
    for (int t = 0; t < 2; ++t)
        #pragma unroll
        for (int kt = 0; kt < 8; ++kt)
            bf[t][kt] = ld_cvt8(w_hh + (size_t)(wave*32 + t*16 + n) * H_ + kt*32 + quad*8);

    __shared__ __align__(16) _Float16 hb[2][256];
    if (tid < 256) hb[0][tid] = (_Float16)0.0f;
    __syncthreads();

    const _Float16* xq = xp2 + ((size_t)b * TBLK_ * H_ + j) * 8;
    _Float16*       hsl = hs + (size_t)b * H_ + j;

    h8 pf = *(const h8*)xq;                 // block 0

#define K2_STEP(T, RB, WB, XV)                                                 \
    {                                                                          \
        const h8* hp = (const h8*)&RB[0];                                      \
        h8 av[8];                                                              \
        _Pragma("unroll")                                                      \
        for (int kt = 0; kt < 8; ++kt) av[kt] = hp[kt*4 + quad];               \
        f32x4 acc[2];                                                          \
        _Pragma("unroll")                                                      \
        for (int t = 0; t < 2; ++t) acc[t] = (f32x4){0,0,0,0};                 \
        _Pragma("unroll")                                                      \
        for (int kt = 0; kt < 8; ++kt)                                         \
            _Pragma("unroll")                                                  \
            for (int t = 0; t < 2; ++t)                                        \
                acc[t] = __builtin_amdgcn_mfma_f32_16x16x32_f16(av[kt], bf[t][kt], acc[t], 0, 0, 0); \
        float vv = tsel ? acc[1][0] : acc[0][0];                               \
        float sv = vv + (XV);                                                  \
        float e  = __expf(2.0f * sv);                                          \
        float hn = fmaf(-2.0f, __builtin_amdgcn_rcpf(e + 1.0f), 1.0f);         \
        _Float16 h16 = (_Float16)hn;                                           \
        if (writer) {                                                          \
            WB[j] = h16;                                                       \
            hsl[(size_t)(T) * BH_] = h16;                                      \
        }                                                                      \
        BAR_LGKM();                                                            \
    }

    for (int tb = 0; tb < TBLK_; ++tb) {
        h8 cur = pf;                         // waits on load issued 1 block ago
        const int tnb = (tb + 1 < TBLK_) ? tb + 1 : TBLK_ - 1;
        pf = *(const h8*)(xq + (size_t)tnb * (H_ * 8));   // in flight for 8 steps
        const int t = tb * 8;
        K2_STEP(t + 0, hb[0], hb[1], (float)cur[0])
        K2_STEP(t + 1, hb[1], hb[0], (float)cur[1])
        K2_STEP(t + 2, hb[0], hb[1], (float)cur[2])
        K2_STEP(t + 3, hb[1], hb[0], (float)cur[3])
        K2_STEP(t + 4, hb[0], hb[1], (float)cur[4])
        K2_STEP(t + 5, hb[1], hb[0], (float)cur[5])
        K2_STEP(t + 6, hb[0], hb[1], (float)cur[6])
        K2_STEP(t + 7, hb[1], hb[0], (float)cur[7])
    }
#undef K2_STEP
}

// ---------------------------------------------------------------------------
// K3: out[TB][128](f32) = hs[TB][256](f16) @ W_out^T + b_out   (MFMA C^T)
// (unchanged from proven baseline)
// ---------------------------------------------------------------------------
__global__ __launch_bounds__(256, 2) void k3_out(
    const _Float16* __restrict__ hs,
    const float* __restrict__ w_out,
    const float* __restrict__ b_out,
    float* __restrict__ out)
{
    const int tid = threadIdx.x;
    const int lane = tid & 63, wave = tid >> 6;
    const int m = lane & 15, quad = lane >> 4;

    h8 af[2][8];
    #pragma unroll
    for (int i = 0; i < 2; ++i)
        #pragma unroll
        for (int kt = 0; kt < 8; ++kt)
            af[i][kt] = ld_cvt8(w_out + (size_t)(wave*32 + i*16 + m) * H_ + kt*32 + quad*8);

    float bias[2][4];
    #pragma unroll
    for (int i = 0; i < 2; ++i)
        #pragma unroll
        for (int r = 0; r < 4; ++r)
            bias[i][r] = b_out[wave*32 + i*16 + quad*4 + r];

    __shared__ __align__(16) float st[2][16][132];

    h8 bf[8];
    {
        const size_t n0 = (size_t)blockIdx.x * 128;
        #pragma unroll
        for (int kt = 0; kt < 8; ++kt)
            bf[kt] = *(const h8*)(hs + (n0 + m) * H_ + kt*32 + quad*8);
    }

    for (int rt = 0; rt < 8; ++rt) {
        const size_t n0 = (size_t)blockIdx.x * 128 + rt * 16;

        h8 cur[8];
        #pragma unroll
        for (int kt = 0; kt < 8; ++kt) cur[kt] = bf[kt];

        if (rt < 7) {
            #pragma unroll
            for (int kt = 0; kt < 8; ++kt)
                bf[kt] = *(const h8*)(hs + (n0 + 16 + m) * H_ + kt*32 + quad*8);
        }

        f32x4 acc[2];
        #pragma unroll
        for (int i = 0; i < 2; ++i) acc[i] = (f32x4){0,0,0,0};
        #pragma unroll
        for (int i = 0; i < 2; ++i)
            #pragma unroll
            for (int kt = 0; kt < 8; ++kt)
                acc[i] = __builtin_amdgcn_mfma_f32_16x16x32_f16(af[i][kt], cur[kt], acc[i], 0, 0, 0);

        const int p = rt & 1;
        #pragma unroll
        for (int i = 0; i < 2; ++i) {
            f32x4 v;
            #pragma unroll
            for (int r = 0; r < 4; ++r) v[r] = acc[i][r] + bias[i][r];
            *(f32x4*)&st[p][m][wave*32 + i*16 + quad*4] = v;
        }
        BAR_LGKM();
        #pragma unroll
        for (int it = 0; it < 2; ++it) {
            int idx = tid + it*256;
            int r = idx >> 5, c4 = (idx & 31) * 4;
            f32x4 v = *(const f32x4*)&st[p][r][c4];
            *(f32x4*)(out + (n0 + r) * NOUT_ + c4) = v;
        }
    }
}

extern "C" void kernel_launch(void* const* d_in, const int* in_sizes, int n_in,
                              void* d_out, int out_size, void* d_ws, size_t ws_size,
                              hipStream_t stream) {
    const float* x     = (const float*)d_in[0];
    const float* w_ih  = (const float*)d_in[1];
    const float* w_hh  = (const float*)d_in[2];
    const float* b_ih  = (const float*)d_in[3];
    const float* b_hh  = (const float*)d_in[4];
    const float* w_out = (const float*)d_in[5];
    const float* b_out = (const float*)d_in[6];

    _Float16* xp2   = (_Float16*)d_ws;                 // 67.1 MB [B][T/8][H][8]
    _Float16* hsbuf = xp2 + (size_t)TB_ * H_;          // 67.1 MB [T][B][H]

    k1_xproj<<<1024, 256, 0, stream>>>(x, w_ih, b_ih, b_hh, xp2);
    k2_scan <<<B_,   512, 0, stream>>>(xp2, w_hh, hsbuf);
    k3_out  <<<1024, 256, 0, stream>>>(hsbuf, w_out, b_out, (float*)d_out);
}